// Round 11
// baseline (79.020 us; speedup 1.0000x reference)
//
#include <hip/hip_runtime.h>
#include <hip/hip_bf16.h>

typedef __bf16 bf16_t;
typedef __attribute__((ext_vector_type(4))) __bf16 bf16x4;
typedef __attribute__((ext_vector_type(8))) __bf16 bf16x8;
typedef __attribute__((ext_vector_type(4))) float f32x4;

#define B_ 8
#define T_ 2048
#define C_ 1024
#define H_ 64

// q-scale: H^-0.5 * log2(e)  (softmax computed in exp2 domain)
#define QSCALE 0.18033688f

// async global->LDS, 16B per lane (used by attn staging only)
__device__ __forceinline__ void dma16(const void* g, void* l) {
  __builtin_amdgcn_global_load_lds(
      (const __attribute__((address_space(1))) void*)g,
      (__attribute__((address_space(3))) void*)l, 16, 0, 0);
}

// ---------------------------------------------------------------------------
// Kernel 1: convert + transpose weights -> Wt[col][k] bf16 (col = wsel*64+h)
// ---------------------------------------------------------------------------
__global__ __launch_bounds__(256) void wprep_kernel(
    const float* __restrict__ Wq, const float* __restrict__ Wk,
    const float* __restrict__ Wv, bf16_t* __restrict__ Wt) {
  __shared__ float tile[64][68];
  const int t  = threadIdx.x;
  const int w  = blockIdx.x >> 4;
  const int k0 = (blockIdx.x & 15) * 64;
  const float* W = (w == 0) ? Wq : ((w == 1) ? Wk : Wv);

#pragma unroll
  for (int i = 0; i < 4; ++i) {
    int kl  = (t >> 4) + 16 * i;
    int col = (t & 15) * 4;
    float4 u = *(const float4*)(W + (size_t)(k0 + kl) * H_ + col);
    tile[kl][col + 0] = u.x; tile[kl][col + 1] = u.y;
    tile[kl][col + 2] = u.z; tile[kl][col + 3] = u.w;
  }
  __syncthreads();
#pragma unroll
  for (int i = 0; i < 4; ++i) {
    int h  = (t >> 4) + 16 * i;
    int kl = (t & 15) * 4;
    bf16x4 v;
    v[0] = (bf16_t)tile[kl + 0][h]; v[1] = (bf16_t)tile[kl + 1][h];
    v[2] = (bf16_t)tile[kl + 2][h]; v[3] = (bf16_t)tile[kl + 3][h];
    *(bf16x4*)(Wt + (size_t)w * 65536 + (size_t)h * C_ + k0 + kl) = v;
  }
}

// ---------------------------------------------------------------------------
// Kernel 2: QKV projection v10 — K-SPLIT x2 for 4 blocks/CU.
// grid 1024 = (row-tile 512) x (K-half 2); block = 4 waves = 32r x 192c,
// 16 phases of BK=32 over this block's K-half.
// Reg-staged A (coalesced global float4 -> regs -> swizzled ds_write ->
// conflict-free ds_read); B reg-prefetched dist-1 (L2-hot Wt).
// Issue order per phase: B(p+1) loads, then A(p+2) loads, compute from
// LDS buf X, ds_write buf X^1 <- A(p+1) regs (2-phase flight), barrier.
// Fully unrolled: all reg-set indices compile-time.
// Output: plain row-major bf16 PARTIALS pb[kh][m][192] (combined later).
// ---------------------------------------------------------------------------
__global__ __launch_bounds__(256) void qkv_kernel(
    const float* __restrict__ x, const bf16_t* __restrict__ Wt,
    bf16_t* __restrict__ pb) {
  __shared__ __align__(16) float xs[2][1024];  // [buf][32 rows x 32 floats]
  const int tid  = threadIdx.x;
  const int wave = tid >> 6;
  const int lane = tid & 63;
  const int l15  = lane & 15;
  const int lq   = lane >> 4;
  const int bid  = blockIdx.x;
  const int row0 = (bid >> 1) * 32;
  const int kh   = bid & 1;
  const int kbase = kh * 512;

  const bf16_t* bp[3];
  int col_[3];
#pragma unroll
  for (int j = 0; j < 3; ++j) {
    col_[j] = wave * 48 + j * 16 + l15;
    bp[j] = Wt + (size_t)col_[j] * C_ + kbase + lq * 8;
  }

  // A staging map: thread -> row sr, 16B granule fg; swizzled ds_write
  const int sr = tid >> 3;
  const int fg = tid & 7;
  const float* asrc = x + (size_t)(row0 + sr) * C_ + kbase + fg * 4;
  const int woff = sr * 32 + ((fg ^ (sr & 7)) << 2);  // float index

  // read swizzle: row r = m*16+l15 -> rs = l15&7
  const int rs = l15 & 7;
  const int ro0 = ((2 * lq) ^ rs) << 2;
  const int ro1 = ((2 * lq + 1) ^ rs) << 2;

  f32x4 acc[2][3];
#pragma unroll
  for (int m = 0; m < 2; ++m)
#pragma unroll
    for (int j = 0; j < 3; ++j) acc[m][j] = (f32x4){0.f, 0.f, 0.f, 0.f};

  bf16x8 breg[2][3];
  float4 regA[2];

  // prologue: A(0) -> buf0; B(0) -> breg[0]; A(1) -> regA[1]
  {
    float4 a0 = *(const float4*)asrc;
    *(float4*)(&xs[0][0] + woff) = a0;
  }
#pragma unroll
  for (int j = 0; j < 3; ++j) breg[0][j] = *(const bf16x8*)bp[j];
  regA[1] = *(const float4*)(asrc + 32);
  __syncthreads();

#pragma unroll
  for (int p = 0; p < 16; ++p) {
    const int X = p & 1;
    // issue B(p+1) FIRST, then A(p+2) (so no wait forces a newer op)
    if (p + 1 < 16) {
#pragma unroll
      for (int j = 0; j < 3; ++j)
        breg[X ^ 1][j] = *(const bf16x8*)(bp[j] + (p + 1) * 32);
    }
    if (p + 2 < 16) regA[X] = *(const float4*)(asrc + (p + 2) * 32);

    // compute phase p from xs[X] and breg[X]
    const float* bufc = &xs[X][0];
    bf16x8 af[2];
#pragma unroll
    for (int m = 0; m < 2; ++m) {
      const float* rowp = bufc + (m * 16 + l15) * 32;
      f32x4 a0 = *(const f32x4*)(rowp + ro0);
      f32x4 a1 = *(const f32x4*)(rowp + ro1);
      bf16x8 a;
      a[0] = (bf16_t)a0[0]; a[1] = (bf16_t)a0[1]; a[2] = (bf16_t)a0[2]; a[3] = (bf16_t)a0[3];
      a[4] = (bf16_t)a1[0]; a[5] = (bf16_t)a1[1]; a[6] = (bf16_t)a1[2]; a[7] = (bf16_t)a1[3];
      af[m] = a;
    }
    __builtin_amdgcn_s_setprio(1);
#pragma unroll
    for (int m = 0; m < 2; ++m)
#pragma unroll
      for (int j = 0; j < 3; ++j)
        acc[m][j] = __builtin_amdgcn_mfma_f32_16x16x32_bf16(af[m], breg[X][j], acc[m][j], 0, 0, 0);
    __builtin_amdgcn_s_setprio(0);

    // write-late: A(p+1) regs (issued at p-1, ~2-phase flight) -> buf X^1
    if (p + 1 < 16) *(float4*)(&xs[X ^ 1][0] + woff) = regA[X ^ 1];
    __syncthreads();
  }

  // epilogue: plain row-major partials
  bf16_t* pbh = pb + (size_t)kh * 16384 * 192;
#pragma unroll
  for (int m = 0; m < 2; ++m)
#pragma unroll
    for (int j = 0; j < 3; ++j)
#pragma unroll
      for (int r = 0; r < 4; ++r) {
        int mm = row0 + m * 16 + lq * 4 + r;
        pbh[(size_t)mm * 192 + col_[j]] = (bf16_t)acc[m][j][r];
      }
}

// ---------------------------------------------------------------------------
// Kernel 2b: combine K-halves + format. Grid 1536:
//  b<512: q (scaled, row-major); b<1024: k (frag-tile); else: v (frag-tile).
// All regions read/write bf16x8 coalesced.
// ---------------------------------------------------------------------------
__global__ __launch_bounds__(256) void qkv_combine(
    const bf16_t* __restrict__ pb, bf16_t* __restrict__ qb,
    bf16_t* __restrict__ kb2, bf16_t* __restrict__ vt2) {
  const int b = blockIdx.x;
  const int tid = threadIdx.x;
  const bf16_t* pb0 = pb;
  const bf16_t* pb1 = pb + (size_t)16384 * 192;

  if (b < 512) {  // q: thread = (m, 8-col group)
    int id = b * 256 + tid;
    int m = id >> 3, cg = id & 7;
    bf16x8 u0 = *(const bf16x8*)(pb0 + (size_t)m * 192 + cg * 8);
    bf16x8 u1 = *(const bf16x8*)(pb1 + (size_t)m * 192 + cg * 8);
    bf16x8 o;
#pragma unroll
    for (int e = 0; e < 8; ++e)
      o[e] = (bf16_t)(((float)u0[e] + (float)u1[e]) * QSCALE);
    *(bf16x8*)(qb + (size_t)m * 64 + cg * 8) = o;
  } else if (b < 1024) {  // k: thread = (m, 8-h group)
    int id = (b - 512) * 256 + tid;
    int m = id >> 3, hg = id & 7;
    bf16x8 u0 = *(const bf16x8*)(pb0 + (size_t)m * 192 + 64 + hg * 8);
    bf16x8 u1 = *(const bf16x8*)(pb1 + (size_t)m * 192 + 64 + hg * 8);
    bf16x8 o;
#pragma unroll
    for (int e = 0; e < 8; ++e)
      o[e] = (bf16_t)((float)u0[e] + (float)u1[e]);
    int bb = m >> 11, t = m & 2047, tile = t >> 6;
    size_t base = ((size_t)bb * 32 + tile) << 12;
    int n = (t >> 4) & 3, l15k = t & 15;
    *(bf16x8*)(kb2 + base + n * 1024 + (hg >> 2) * 512 + (hg & 3) * 128 + l15k * 8) = o;
  } else {  // v: thread = (h, 8-row group) -> contiguous dest
    int id = (b - 1024) * 256 + tid;
    int h = id & 63, mg = id >> 6;
    int m0 = mg * 8;
    bf16x8 o;
#pragma unroll
    for (int i = 0; i < 8; ++i) {
      float s = (float)pb0[(size_t)(m0 + i) * 192 + 128 + h] +
                (float)pb1[(size_t)(m0 + i) * 192 + 128 + h];
      o[i] = (bf16_t)s;
    }
    int bb = m0 >> 11, t0 = m0 & 2047, tile = t0 >> 6, tl0 = t0 & 63;
    size_t base = ((size_t)bb * 32 + tile) << 12;
    int k0 = tl0 >> 5, lqv = (tl0 >> 3) & 3;
    int nh = h >> 4, l15v = h & 15;
    *(bf16x8*)(vt2 + base + nh * 1024 + k0 * 512 + lqv * 128 + l15v * 8) = o;
  }
}

// ---------------------------------------------------------------------------
// Kernel 3a: causal flash attention PARTIALS, split-4, LDS-shared K/V (DMA).
// Grid 1024 = (b<<7)|(qi<<2)|ch. Block = 256 threads = 4 waves (rg = wave).
// ---------------------------------------------------------------------------
__global__ __launch_bounds__(256) void attn_partial(
    const bf16_t* __restrict__ qb, const bf16_t* __restrict__ kb2,
    const bf16_t* __restrict__ vt2, bf16_t* __restrict__ opart,
    float* __restrict__ ml) {
  __shared__ bf16_t kvlds[2][8192];   // [buf][ K:0..4095 | V:4096..8191 ]
  __shared__ bf16_t plds[4][16][72];
  const int wave = threadIdx.x >> 6;  // = rg
  const int lane = threadIdx.x & 63;
  const int l15  = lane & 15;
  const int lq   = lane >> 4;
  const int bid  = blockIdx.x;
  const int b    = bid >> 7;
  const int qi   = (bid >> 2) & 31;
  const int ch   = bid & 3;
  const bf16_t* qB = qb + (size_t)b * T_ * H_;
  const int rowbase = qi * 64 + wave * 16;

  bf16x8 qf[2];
#pragma unroll
  for (int k0 = 0; k0 < 2; ++k0)
    qf[k0] = *(const bf16x8*)(qB + (size_t)(rowbase + l15) * H_ + k0 * 32 + lq * 8);

  float m_run = -1e30f;
  float l_part = 0.f;
  f32x4 oacc[4];
#pragma unroll
  for (int nh = 0; nh < 4; ++nh) oacc[nh] = (f32x4){0.f, 0.f, 0.f, 0.f};

  const int nt = (qi >= ch) ? ((qi - ch) >> 2) + 1 : 0;
  const size_t tb = ((size_t)b * 32) << 12;

#define STAGE(KT, BUF)                                                        \
  {                                                                           \
    const bf16_t* kg = kb2 + tb + ((size_t)(KT) << 12) + wave * 1024 + lane * 8; \
    const bf16_t* vg = vt2 + tb + ((size_t)(KT) << 12) + wave * 1024 + lane * 8; \
    bf16_t* kl = &kvlds[BUF][wave * 1024];                                    \
    bf16_t* vl = &kvlds[BUF][4096 + wave * 1024];                             \
    dma16(kg, kl);        dma16(kg + 512, kl + 512);                          \
    dma16(vg, vl);        dma16(vg + 512, vl + 512);                          \
  }

  if (nt > 0) STAGE(ch, 0);
  __syncthreads();

  int kt = ch;
  for (int it = 0; it < nt; ++it, kt += 4) {
    const int buf = it & 1;
    if (it + 1 < nt) STAGE(kt + 4, buf ^ 1);

    const bf16_t* klp = &kvlds[buf][0];
    const bf16_t* vlp = &kvlds[buf][4096];

    bf16x8 kf[4][2];
#pragma unroll
    for (int n = 0; n < 4; ++n)
#pragma unroll
      for (int k0 = 0; k0 < 2; ++k0)
        kf[n][k0] = *(const bf16x8*)(klp + n * 1024 + k0 * 512 + lq * 128 + l15 * 8);

    f32x4 sacc[4];
#pragma unroll
    for (int n = 0; n < 4; ++n) sacc[n] = (f32x4){0.f, 0.f, 0.f, 0.f};
    __builtin_amdgcn_s_setprio(1);
#pragma unroll
    for (int n = 0; n < 4; ++n)
#pragma unroll
      for (int k0 = 0; k0 < 2; ++k0)
        sacc[n] = __builtin_amdgcn_mfma_f32_16x16x32_bf16(kf[n][k0], qf[k0], sacc[n], 0, 0, 0);
    __builtin_amdgcn_s_setprio(0);

    bf16x8 vf[4][2];
#pragma unroll
    for (int nh = 0; nh < 4; ++nh)
#pragma unroll
      for (int k0 = 0; k0 < 2; ++k0)
        vf[nh][k0] = *(const bf16x8*)(vlp + nh * 1024 + k0 * 512 + lq * 128 + l15 * 8);

    if (kt == qi) {
#pragma unroll
      for (int n = 0; n < 4; ++n)
#pragma unroll
        for (int r = 0; r < 4; ++r)
          if (n * 16 + lq * 4 + r > wave * 16 + l15) sacc[n][r] = -1e30f;
    }

    float mx = -1e30f;
#pragma unroll
    for (int n = 0; n < 4; ++n)
#pragma unroll
      for (int r = 0; r < 4; ++r) mx = fmaxf(mx, sacc[n][r]);
    mx = fmaxf(mx, __shfl_xor(mx, 16));
    mx = fmaxf(mx, __shfl_xor(mx, 32));

    if (__any(mx > m_run)) {
      float mnew = fmaxf(m_run, mx);
      float corr = exp2f(m_run - mnew);
      l_part *= corr;
      m_run = mnew;
      float corr4[4];
#pragma unroll
      for (int r = 0; r < 4; ++r) corr4[r] = __shfl(corr, lq * 4 + r);
#pragma unroll
      for (int nh = 0; nh < 4; ++nh)
#pragma unroll
        for (int r = 0; r < 4; ++r) oacc[nh][r] *= corr4[r];
    }

    float psum = 0.f;
#pragma unroll
    for (int n = 0; n < 4; ++n)
#pragma unroll
      for (int r = 0; r < 4; ++r) {
        float p = exp2f(sacc[n][r] - m_run);
        sacc[n][r] = p;
        psum += p;
      }
    l_part += psum;

#pragma unroll
    for (int n = 0; n < 4; ++n) {
      bf16x4 pk;
#pragma unroll
      for (int r = 0; r < 4; ++r) pk[r] = (bf16_t)sacc[n][r];
      *(bf16x4*)&plds[wave][l15][n * 16 + lq * 4] = pk;
    }
    bf16x8 pa[2];
    pa[0] = *(const bf16x8*)&plds[wave][l15][lq * 8];
    pa[1] = *(const bf16x8*)&plds[wave][l15][32 + lq * 8];

    __builtin_amdgcn_s_setprio(1);
#pragma unroll
    for (int nh = 0; nh < 4; ++nh)
#pragma unroll
      for (int k0 = 0; k0 < 2; ++k0)
        oacc[nh] = __builtin_amdgcn_mfma_f32_16x16x32_bf16(pa[k0], vf[nh][k0], oacc[nh], 0, 0, 0);
    __builtin_amdgcn_s_setprio(0);

    __syncthreads();
  }
#undef STAGE

  float l_tot = l_part + __shfl_xor(l_part, 16);
  l_tot += __shfl_xor(l_tot, 32);

  const size_t prow = (size_t)bid * 64 + wave * 16;
#pragma unroll
  for (int r = 0; r < 4; ++r)
#pragma unroll
    for (int nh = 0; nh < 4; ++nh)
      opart[(prow + lq * 4 + r) * 64 + nh * 16 + l15] = (bf16_t)oacc[nh][r];
  if (lq == 0) {
    ml[(prow + l15) * 2 + 0] = m_run;
    ml[(prow + l15) * 2 + 1] = l_tot;
  }
}

// ---------------------------------------------------------------------------
// Kernel 3b: combine 4 kv-chunk partials per (b, qi). Grid 1024.
// ---------------------------------------------------------------------------
__global__ __launch_bounds__(256) void attn_combine(
    const bf16_t* __restrict__ opart, const float* __restrict__ ml,
    float* __restrict__ out) {
  const int bid = blockIdx.x;
  const int cid = bid >> 2;           // (b<<5)|qi
  const int rq  = bid & 3;
  const int b   = cid >> 5;
  const int qi  = cid & 31;
  const int row = rq * 16 + (threadIdx.x >> 4);
  const int c4  = (threadIdx.x & 15) * 4;

  float o0 = 0.f, o1 = 0.f, o2 = 0.f, o3 = 0.f;
  float M = -1e30f, L = 0.f;
#pragma unroll
  for (int s = 0; s < 4; ++s) {
    const size_t prow = (size_t)(cid * 4 + s) * 64 + row;
    float ms = ml[prow * 2 + 0];
    float ls = ml[prow * 2 + 1];
    float Mn = fmaxf(M, ms);
    float a  = exp2f(M - Mn);
    float bs = exp2f(ms - Mn);
    bf16x4 ov = *(const bf16x4*)(opart + prow * 64 + c4);
    o0 = o0 * a + (float)ov[0] * bs;
    o1 = o1 * a + (float)ov[1] * bs;
    o2 = o2 * a + (float)ov[2] * bs;
    o3 = o3 * a + (float)ov[3] * bs;
    L = L * a + ls * bs;
    M = Mn;
  }
  float inv = 1.0f / L;
  float4 v = {o0 * inv, o1 * inv, o2 * inv, o3 * inv};
  *(float4*)(out + ((size_t)b * T_ + qi * 64 + row) * H_ + c4) = v;
}

// ---------------------------------------------------------------------------
extern "C" void kernel_launch(void* const* d_in, const int* in_sizes, int n_in,
                              void* d_out, int out_size, void* d_ws, size_t ws_size,
                              hipStream_t stream) {
  const float* x  = (const float*)d_in[0];
  const float* Wq = (const float*)d_in[1];
  const float* Wk = (const float*)d_in[2];
  const float* Wv = (const float*)d_in[3];

  char* ws = (char*)d_ws;
  bf16_t* Wt    = (bf16_t*)(ws);                      // 384 KB
  bf16_t* pbuf  = (bf16_t*)(ws + (1u << 20));         // 12.6 MB (2 K-half partials)
  bf16_t* qb    = (bf16_t*)(ws + 14u * (1u << 20));   // 2 MB (q * QSCALE)
  bf16_t* kb2   = (bf16_t*)(ws + 16u * (1u << 20));   // 2 MB (frag-tile order)
  bf16_t* vt2   = (bf16_t*)(ws + 18u * (1u << 20));   // 2 MB (frag-tile order)
  bf16_t* opart = (bf16_t*)(ws + 20u * (1u << 20));   // 8 MB
  float*  mlbuf = (float*)(ws + 28u * (1u << 20));    // 512 KB
  float*  outp  = (float*)d_out;

  hipLaunchKernelGGL(wprep_kernel, dim3(48), dim3(256), 0, stream, Wq, Wk, Wv, Wt);
  hipLaunchKernelGGL(qkv_kernel, dim3(1024), dim3(256), 0, stream, x, Wt, pbuf);
  hipLaunchKernelGGL(qkv_combine, dim3(1536), dim3(256), 0, stream, pbuf, qb, kb2, vt2);
  hipLaunchKernelGGL(attn_partial, dim3(1024), dim3(256), 0, stream, qb, kb2, vt2, opart, mlbuf);
  hipLaunchKernelGGL(attn_combine, dim3(1024), dim3(256), 0, stream, opart, mlbuf, outp);
}

// Round 12
// 61.059 us; speedup vs baseline: 1.2941x; 1.2941x over previous
//
#include <hip/hip_runtime.h>
#include <hip/hip_bf16.h>

typedef __bf16 bf16_t;
typedef __attribute__((ext_vector_type(4))) __bf16 bf16x4;
typedef __attribute__((ext_vector_type(8))) __bf16 bf16x8;
typedef __attribute__((ext_vector_type(4))) float f32x4;

#define B_ 8
#define T_ 2048
#define C_ 1024
#define H_ 64

// q-scale: H^-0.5 * log2(e)  (softmax computed in exp2 domain)
#define QSCALE 0.18033688f

// async global->LDS, 16B per lane (attn staging)
__device__ __forceinline__ void dma16(const void* g, void* l) {
  __builtin_amdgcn_global_load_lds(
      (const __attribute__((address_space(1))) void*)g,
      (__attribute__((address_space(3))) void*)l, 16, 0, 0);
}

// ---------------------------------------------------------------------------
// Kernel 1: convert + transpose weights -> Wt[col][k] bf16 (col = wsel*64+h)
// ---------------------------------------------------------------------------
__global__ __launch_bounds__(256) void wprep_kernel(
    const float* __restrict__ Wq, const float* __restrict__ Wk,
    const float* __restrict__ Wv, bf16_t* __restrict__ Wt) {
  __shared__ float tile[64][68];
  const int t  = threadIdx.x;
  const int w  = blockIdx.x >> 4;
  const int k0 = (blockIdx.x & 15) * 64;
  const float* W = (w == 0) ? Wq : ((w == 1) ? Wk : Wv);

#pragma unroll
  for (int i = 0; i < 4; ++i) {
    int kl  = (t >> 4) + 16 * i;
    int col = (t & 15) * 4;
    float4 u = *(const float4*)(W + (size_t)(k0 + kl) * H_ + col);
    tile[kl][col + 0] = u.x; tile[kl][col + 1] = u.y;
    tile[kl][col + 2] = u.z; tile[kl][col + 3] = u.w;
  }
  __syncthreads();
#pragma unroll
  for (int i = 0; i < 4; ++i) {
    int h  = (t >> 4) + 16 * i;
    int kl = (t & 15) * 4;
    bf16x4 v;
    v[0] = (bf16_t)tile[kl + 0][h]; v[1] = (bf16_t)tile[kl + 1][h];
    v[2] = (bf16_t)tile[kl + 2][h]; v[3] = (bf16_t)tile[kl + 3][h];
    *(bf16x4*)(Wt + (size_t)w * 65536 + (size_t)h * C_ + k0 + kl) = v;
  }
}

// ---------------------------------------------------------------------------
// Kernel 2: QKV projection — EXACT v3 core (R3, proven 33 µs / 0.0156).
// Grid 512 (2 blocks/CU). Block = 32 rows x 192 cols, 4 waves; wave =
// 32r x 48c = 2x3 frags of 16x16x32 MFMA. BK=32, dist-1 everywhere:
// x staged global->reg->swizzled ds_write (both-sides swizzle: coalesced
// global AND conflict-free LDS); B-frags register-prefetched dist-1.
// ONLY the epilogue differs from v3: q *QSCALE row-major; K/V emitted in
// FRAGMENT-TILE order (8KB per 64-token tile) for attn's DMA staging:
//   K tile elem [n*1024+k0*512+lq*128+l15*8+e] = K[tile*64+n*16+l15][k0*32+lq*8+e]
//   V tile elem [nh*1024+k0*512+lq*128+l15*8+e] = V^T[nh*16+l15][k0*32+lq*8+e]
// ---------------------------------------------------------------------------
__global__ __launch_bounds__(256) void qkv_kernel(
    const float* __restrict__ x, const bf16_t* __restrict__ Wt,
    bf16_t* __restrict__ qb, bf16_t* __restrict__ kb2, bf16_t* __restrict__ vt2) {
  __shared__ float xs[2][32][32];  // [buf][row][k], swizzled: byte^((row&7)<<4)
  const int tid  = threadIdx.x;
  const int wave = tid >> 6;
  const int lane = tid & 63;
  const int l15  = lane & 15;
  const int lq   = lane >> 4;
  const int row0 = blockIdx.x * 32;

  // per-n-frag B info (col -> which matrix, which head col)
  int wsel_[3], h_[3];
  const bf16_t* bp[3];
#pragma unroll
  for (int j = 0; j < 3; ++j) {
    int col  = wave * 48 + j * 16 + l15;
    wsel_[j] = col >> 6;
    h_[j]    = col & 63;
    bp[j] = Wt + (size_t)col * C_ + lq * 8;
  }

  // staging map: thread -> (row sr, linear float col sfc); write swizzled
  const int sr  = tid >> 3;
  const int sfc = (tid & 7) * 4;
  const float* src = x + (size_t)(row0 + sr) * C_ + sfc;
  const int dstoff = sr * 32 + (sfc ^ ((sr & 7) * 4));  // float index in tile

  f32x4 acc[2][3];
#pragma unroll
  for (int m = 0; m < 2; ++m)
#pragma unroll
    for (int j = 0; j < 3; ++j) acc[m][j] = (f32x4){0.f, 0.f, 0.f, 0.f};

  // prologue: stage k-step 0 into buf0; preload B[0]
  {
    float4 v = *(const float4*)src;
    *(float4*)(&xs[0][0][0] + dstoff) = v;
  }
  bf16x8 bcur[3];
#pragma unroll
  for (int j = 0; j < 3; ++j) bcur[j] = *(const bf16x8*)bp[j];
  __syncthreads();

  for (int k = 0; k < 32; ++k) {
    const int kn = k + 1;
    float4 vstage;
    bf16x8 bnext[3];
    if (kn < 32) {
      vstage = *(const float4*)(src + kn * 32);  // issue early, lands by barrier
#pragma unroll
      for (int j = 0; j < 3; ++j) bnext[j] = *(const bf16x8*)(bp[j] + kn * 32);
    }

    // A-frags from swizzled LDS
    const char* base = (const char*)&xs[k & 1][0][0];
    bf16x8 af[2];
#pragma unroll
    for (int m = 0; m < 2; ++m) {
      int r  = m * 16 + l15;
      int sw = (r & 7) << 4;
      f32x4 a0 = *(const f32x4*)(base + r * 128 + ((lq * 32) ^ sw));
      f32x4 a1 = *(const f32x4*)(base + r * 128 + ((lq * 32 + 16) ^ sw));
      bf16x8 a;
      a[0] = (bf16_t)a0[0]; a[1] = (bf16_t)a0[1]; a[2] = (bf16_t)a0[2]; a[3] = (bf16_t)a0[3];
      a[4] = (bf16_t)a1[0]; a[5] = (bf16_t)a1[1]; a[6] = (bf16_t)a1[2]; a[7] = (bf16_t)a1[3];
      af[m] = a;
    }

#pragma unroll
    for (int m = 0; m < 2; ++m)
#pragma unroll
      for (int j = 0; j < 3; ++j)
        acc[m][j] = __builtin_amdgcn_mfma_f32_16x16x32_bf16(af[m], bcur[j], acc[m][j], 0, 0, 0);

    if (kn < 32) {
      *(float4*)(&xs[kn & 1][0][0] + dstoff) = vstage;  // write-late
#pragma unroll
      for (int j = 0; j < 3; ++j) bcur[j] = bnext[j];
    }
    __syncthreads();
  }

  // epilogue: q row-major * QSCALE; K/V in fragment-tile order
#pragma unroll
  for (int m = 0; m < 2; ++m)
#pragma unroll
    for (int j = 0; j < 3; ++j)
#pragma unroll
      for (int r = 0; r < 4; ++r) {
        int mm  = row0 + m * 16 + lq * 4 + r;
        float v = acc[m][j][r];
        int h   = h_[j];
        if (wsel_[j] == 0) {
          qb[(size_t)mm * H_ + h] = (bf16_t)(v * QSCALE);
        } else {
          int bb = mm >> 11, t = mm & 2047;
          int tile = t >> 6;
          size_t base2 = ((size_t)bb * 32 + tile) << 12;
          if (wsel_[j] == 1) {
            int n = (t >> 4) & 3, l15k = t & 15;
            int k0 = h >> 5, lqk = (h >> 3) & 3, e = h & 7;
            kb2[base2 + n * 1024 + k0 * 512 + lqk * 128 + l15k * 8 + e] = (bf16_t)v;
          } else {
            int tl = t & 63;
            int k0 = tl >> 5, lqv = (tl >> 3) & 3, ev = tl & 7;
            int nh = h >> 4, l15v = h & 15;
            vt2[base2 + nh * 1024 + k0 * 512 + lqv * 128 + l15v * 8 + ev] = (bf16_t)v;
          }
        }
      }
}

// ---------------------------------------------------------------------------
// Kernel 3a: causal flash attention PARTIALS, split-4, LDS-shared K/V (DMA).
// Grid 1024 = (b<<7)|(qi<<2)|ch. Block = 256 threads = 4 waves (rg = wave).
// (unchanged from R10)
// ---------------------------------------------------------------------------
__global__ __launch_bounds__(256) void attn_partial(
    const bf16_t* __restrict__ qb, const bf16_t* __restrict__ kb2,
    const bf16_t* __restrict__ vt2, bf16_t* __restrict__ opart,
    float* __restrict__ ml) {
  __shared__ bf16_t kvlds[2][8192];   // [buf][ K:0..4095 | V:4096..8191 ]
  __shared__ bf16_t plds[4][16][72];
  const int wave = threadIdx.x >> 6;  // = rg
  const int lane = threadIdx.x & 63;
  const int l15  = lane & 15;
  const int lq   = lane >> 4;
  const int bid  = blockIdx.x;
  const int b    = bid >> 7;
  const int qi   = (bid >> 2) & 31;
  const int ch   = bid & 3;
  const bf16_t* qB = qb + (size_t)b * T_ * H_;
  const int rowbase = qi * 64 + wave * 16;

  bf16x8 qf[2];
#pragma unroll
  for (int k0 = 0; k0 < 2; ++k0)
    qf[k0] = *(const bf16x8*)(qB + (size_t)(rowbase + l15) * H_ + k0 * 32 + lq * 8);

  float m_run = -1e30f;
  float l_part = 0.f;
  f32x4 oacc[4];
#pragma unroll
  for (int nh = 0; nh < 4; ++nh) oacc[nh] = (f32x4){0.f, 0.f, 0.f, 0.f};

  const int nt = (qi >= ch) ? ((qi - ch) >> 2) + 1 : 0;
  const size_t tb = ((size_t)b * 32) << 12;

#define STAGE(KT, BUF)                                                        \
  {                                                                           \
    const bf16_t* kg = kb2 + tb + ((size_t)(KT) << 12) + wave * 1024 + lane * 8; \
    const bf16_t* vg = vt2 + tb + ((size_t)(KT) << 12) + wave * 1024 + lane * 8; \
    bf16_t* kl = &kvlds[BUF][wave * 1024];                                    \
    bf16_t* vl = &kvlds[BUF][4096 + wave * 1024];                             \
    dma16(kg, kl);        dma16(kg + 512, kl + 512);                          \
    dma16(vg, vl);        dma16(vg + 512, vl + 512);                          \
  }

  if (nt > 0) STAGE(ch, 0);
  __syncthreads();

  int kt = ch;
  for (int it = 0; it < nt; ++it, kt += 4) {
    const int buf = it & 1;
    if (it + 1 < nt) STAGE(kt + 4, buf ^ 1);

    const bf16_t* klp = &kvlds[buf][0];
    const bf16_t* vlp = &kvlds[buf][4096];

    bf16x8 kf[4][2];
#pragma unroll
    for (int n = 0; n < 4; ++n)
#pragma unroll
      for (int k0 = 0; k0 < 2; ++k0)
        kf[n][k0] = *(const bf16x8*)(klp + n * 1024 + k0 * 512 + lq * 128 + l15 * 8);

    f32x4 sacc[4];
#pragma unroll
    for (int n = 0; n < 4; ++n) sacc[n] = (f32x4){0.f, 0.f, 0.f, 0.f};
    __builtin_amdgcn_s_setprio(1);
#pragma unroll
    for (int n = 0; n < 4; ++n)
#pragma unroll
      for (int k0 = 0; k0 < 2; ++k0)
        sacc[n] = __builtin_amdgcn_mfma_f32_16x16x32_bf16(kf[n][k0], qf[k0], sacc[n], 0, 0, 0);
    __builtin_amdgcn_s_setprio(0);

    bf16x8 vf[4][2];
#pragma unroll
    for (int nh = 0; nh < 4; ++nh)
#pragma unroll
      for (int k0 = 0; k0 < 2; ++k0)
        vf[nh][k0] = *(const bf16x8*)(vlp + nh * 1024 + k0 * 512 + lq * 128 + l15 * 8);

    if (kt == qi) {
#pragma unroll
      for (int n = 0; n < 4; ++n)
#pragma unroll
        for (int r = 0; r < 4; ++r)
          if (n * 16 + lq * 4 + r > wave * 16 + l15) sacc[n][r] = -1e30f;
    }

    float mx = -1e30f;
#pragma unroll
    for (int n = 0; n < 4; ++n)
#pragma unroll
      for (int r = 0; r < 4; ++r) mx = fmaxf(mx, sacc[n][r]);
    mx = fmaxf(mx, __shfl_xor(mx, 16));
    mx = fmaxf(mx, __shfl_xor(mx, 32));

    if (__any(mx > m_run)) {
      float mnew = fmaxf(m_run, mx);
      float corr = exp2f(m_run - mnew);
      l_part *= corr;
      m_run = mnew;
      float corr4[4];
#pragma unroll
      for (int r = 0; r < 4; ++r) corr4[r] = __shfl(corr, lq * 4 + r);
#pragma unroll
      for (int nh = 0; nh < 4; ++nh)
#pragma unroll
        for (int r = 0; r < 4; ++r) oacc[nh][r] *= corr4[r];
    }

    float psum = 0.f;
#pragma unroll
    for (int n = 0; n < 4; ++n)
#pragma unroll
      for (int r = 0; r < 4; ++r) {
        float p = exp2f(sacc[n][r] - m_run);
        sacc[n][r] = p;
        psum += p;
      }
    l_part += psum;

#pragma unroll
    for (int n = 0; n < 4; ++n) {
      bf16x4 pk;
#pragma unroll
      for (int r = 0; r < 4; ++r) pk[r] = (bf16_t)sacc[n][r];
      *(bf16x4*)&plds[wave][l15][n * 16 + lq * 4] = pk;
    }
    bf16x8 pa[2];
    pa[0] = *(const bf16x8*)&plds[wave][l15][lq * 8];
    pa[1] = *(const bf16x8*)&plds[wave][l15][32 + lq * 8];

    __builtin_amdgcn_s_setprio(1);
#pragma unroll
    for (int nh = 0; nh < 4; ++nh)
#pragma unroll
      for (int k0 = 0; k0 < 2; ++k0)
        oacc[nh] = __builtin_amdgcn_mfma_f32_16x16x32_bf16(pa[k0], vf[nh][k0], oacc[nh], 0, 0, 0);
    __builtin_amdgcn_s_setprio(0);

    __syncthreads();
  }
#undef STAGE

  float l_tot = l_part + __shfl_xor(l_part, 16);
  l_tot += __shfl_xor(l_tot, 32);

  const size_t prow = (size_t)bid * 64 + wave * 16;
#pragma unroll
  for (int r = 0; r < 4; ++r)
#pragma unroll
    for (int nh = 0; nh < 4; ++nh)
      opart[(prow + lq * 4 + r) * 64 + nh * 16 + l15] = (bf16_t)oacc[nh][r];
  if (lq == 0) {
    ml[(prow + l15) * 2 + 0] = m_run;
    ml[(prow + l15) * 2 + 1] = l_tot;
  }
}

// ---------------------------------------------------------------------------
// Kernel 3b: combine 4 kv-chunk partials per (b, qi). Grid 1024.
// ---------------------------------------------------------------------------
__global__ __launch_bounds__(256) void attn_combine(
    const bf16_t* __restrict__ opart, const float* __restrict__ ml,
    float* __restrict__ out) {
  const int bid = blockIdx.x;
  const int cid = bid >> 2;           // (b<<5)|qi
  const int rq  = bid & 3;
  const int b   = cid >> 5;
  const int qi  = cid & 31;
  const int row = rq * 16 + (threadIdx.x >> 4);
  const int c4  = (threadIdx.x & 15) * 4;

  float o0 = 0.f, o1 = 0.f, o2 = 0.f, o3 = 0.f;
  float M = -1e30f, L = 0.f;
#pragma unroll
  for (int s = 0; s < 4; ++s) {
    const size_t prow = (size_t)(cid * 4 + s) * 64 + row;
    float ms = ml[prow * 2 + 0];
    float ls = ml[prow * 2 + 1];
    float Mn = fmaxf(M, ms);
    float a  = exp2f(M - Mn);
    float bs = exp2f(ms - Mn);
    bf16x4 ov = *(const bf16x4*)(opart + prow * 64 + c4);
    o0 = o0 * a + (float)ov[0] * bs;
    o1 = o1 * a + (float)ov[1] * bs;
    o2 = o2 * a + (float)ov[2] * bs;
    o3 = o3 * a + (float)ov[3] * bs;
    L = L * a + ls * bs;
    M = Mn;
  }
  float inv = 1.0f / L;
  float4 v = {o0 * inv, o1 * inv, o2 * inv, o3 * inv};
  *(float4*)(out + ((size_t)b * T_ + qi * 64 + row) * H_ + c4) = v;
}

// ---------------------------------------------------------------------------
extern "C" void kernel_launch(void* const* d_in, const int* in_sizes, int n_in,
                              void* d_out, int out_size, void* d_ws, size_t ws_size,
                              hipStream_t stream) {
  const float* x  = (const float*)d_in[0];
  const float* Wq = (const float*)d_in[1];
  const float* Wk = (const float*)d_in[2];
  const float* Wv = (const float*)d_in[3];

  char* ws = (char*)d_ws;
  bf16_t* Wt    = (bf16_t*)(ws);                     // 384 KB
  bf16_t* qb    = (bf16_t*)(ws + (1u << 20));        // 2 MB (q * QSCALE)
  bf16_t* kb2   = (bf16_t*)(ws + 3u * (1u << 20));   // 2 MB (frag-tile order)
  bf16_t* vt2   = (bf16_t*)(ws + 5u * (1u << 20));   // 2 MB (frag-tile order)
  bf16_t* opart = (bf16_t*)(ws + 8u * (1u << 20));   // 8 MB
  float*  mlbuf = (float*)(ws + 17u * (1u << 20));   // 512 KB
  float*  outp  = (float*)d_out;

  hipLaunchKernelGGL(wprep_kernel, dim3(48), dim3(256), 0, stream, Wq, Wk, Wv, Wt);
  hipLaunchKernelGGL(qkv_kernel, dim3(512), dim3(256), 0, stream, x, Wt, qb, kb2, vt2);
  hipLaunchKernelGGL(attn_partial, dim3(1024), dim3(256), 0, stream, qb, kb2, vt2, opart, mlbuf);
  hipLaunchKernelGGL(attn_combine, dim3(1024), dim3(256), 0, stream, opart, mlbuf, outp);
}

// Round 13
// 46.958 us; speedup vs baseline: 1.6828x; 1.3003x over previous
//
#include <hip/hip_runtime.h>
#include <hip/hip_bf16.h>

typedef __bf16 bf16_t;
typedef __attribute__((ext_vector_type(4))) __bf16 bf16x4;
typedef __attribute__((ext_vector_type(8))) __bf16 bf16x8;
typedef __attribute__((ext_vector_type(4))) float f32x4;

#define B_ 8
#define T_ 2048
#define C_ 1024
#define H_ 64

// q-scale: H^-0.5 * log2(e)  (softmax computed in exp2 domain)
#define QSCALE 0.18033688f

// async global->LDS, 16B per lane. LDS dest = wave-uniform base + lane*16.
__device__ __forceinline__ void dma16(const void* g, void* l) {
  __builtin_amdgcn_global_load_lds(
      (const __attribute__((address_space(1))) void*)g,
      (__attribute__((address_space(3))) void*)l, 16, 0, 0);
}

// ---------------------------------------------------------------------------
// Kernel 1: convert + transpose weights -> Wt[col][k] bf16 (col = wsel*64+h)
// ---------------------------------------------------------------------------
__global__ __launch_bounds__(256) void wprep_kernel(
    const float* __restrict__ Wq, const float* __restrict__ Wk,
    const float* __restrict__ Wv, bf16_t* __restrict__ Wt) {
  __shared__ float tile[64][68];
  const int t  = threadIdx.x;
  const int w  = blockIdx.x >> 4;
  const int k0 = (blockIdx.x & 15) * 64;
  const float* W = (w == 0) ? Wq : ((w == 1) ? Wk : Wv);

#pragma unroll
  for (int i = 0; i < 4; ++i) {
    int kl  = (t >> 4) + 16 * i;
    int col = (t & 15) * 4;
    float4 u = *(const float4*)(W + (size_t)(k0 + kl) * H_ + col);
    tile[kl][col + 0] = u.x; tile[kl][col + 1] = u.y;
    tile[kl][col + 2] = u.z; tile[kl][col + 3] = u.w;
  }
  __syncthreads();
#pragma unroll
  for (int i = 0; i < 4; ++i) {
    int h  = (t >> 4) + 16 * i;
    int kl = (t & 15) * 4;
    bf16x4 v;
    v[0] = (bf16_t)tile[kl + 0][h]; v[1] = (bf16_t)tile[kl + 1][h];
    v[2] = (bf16_t)tile[kl + 2][h]; v[3] = (bf16_t)tile[kl + 3][h];
    *(bf16x4*)(Wt + (size_t)w * 65536 + (size_t)h * C_ + k0 + kl) = v;
  }
}

// ---------------------------------------------------------------------------
// Kernel 2: QKV v12 — TCC-request-count attack.
// Grid 256 x 512 threads (8 waves: wr=wave>>2 row-half, wc=wave&3 col-group).
// BM=64, BN=192, BK=64 -> 16 phases, 12 MFMA/wave/phase.
// ALL staging via global_load_lds with COALESCED full-line sources:
//   A: 16KB/phase (2 dma/lane), buffers x3 (dist-2), XOR-swz g^(row&15)
//   B: 24KB/phase (3 dma/lane), buffers x3 (dist-2), XOR-swz g^(col&7)
// Phase top: s_waitcnt vmcnt(5) (forces A(p),B(p); leaves p+1 flying) +
// raw s_barrier. Tail phases issue dummy DMAs to scratch (uniform counts).
// B re-read drops 196->98 MB and is full-line: ~2.7M L2 requests vs 6.1M.
// ---------------------------------------------------------------------------
__global__ __launch_bounds__(512) void qkv_kernel(
    const float* __restrict__ x, const bf16_t* __restrict__ Wt,
    bf16_t* __restrict__ qb, bf16_t* __restrict__ kb2, bf16_t* __restrict__ vt2) {
  __shared__ __align__(16) char lds[131072];  // A:3x16K | B:3x24K | scr:8K
  const int tid  = threadIdx.x;
  const int wave = tid >> 6;
  const int lane = tid & 63;
  const int l15  = lane & 15;
  const int lq   = lane >> 4;
  const int wr   = wave >> 2;
  const int wc   = wave & 3;
  const int row0 = blockIdx.x * 64;

  char* Ab[3] = {lds, lds + 16384, lds + 32768};
  char* Bb[3] = {lds + 49152, lds + 73728, lds + 98304};
  char* scr   = lds + 122880;

#define QKV_STAGE_B(T, BI) do {                                              \
    char* bb_ = Bb[BI];                                                      \
    _Pragma("unroll")                                                        \
    for (int r_ = 0; r_ < 3; ++r_) {                                         \
      int slot_ = r_ * 512 + tid;                                            \
      int col_  = slot_ >> 3;                                                \
      int g_    = slot_ & 7;                                                 \
      dma16(Wt + (size_t)col_ * C_ + (T) * 64 + ((g_ ^ (col_ & 7)) << 3),    \
            bb_ + (r_ * 512 + wave * 64) * 16);                              \
    } } while (0)

#define QKV_STAGE_A(T, BI) do {                                              \
    char* ab_ = Ab[BI];                                                      \
    _Pragma("unroll")                                                        \
    for (int r_ = 0; r_ < 2; ++r_) {                                         \
      int slot_ = r_ * 512 + tid;                                            \
      int row_  = slot_ >> 4;                                                \
      int g_    = slot_ & 15;                                                \
      dma16(x + (size_t)(row0 + row_) * C_ + (T) * 64 + ((g_ ^ (row_ & 15)) << 2), \
            ab_ + (r_ * 512 + wave * 64) * 16);                              \
    } } while (0)

#define QKV_STAGE_B_DUMMY() do {                                             \
    _Pragma("unroll")                                                        \
    for (int r_ = 0; r_ < 3; ++r_) dma16(Wt + tid * 8, scr + wave * 1024);   \
    } while (0)
#define QKV_STAGE_A_DUMMY() do {                                             \
    _Pragma("unroll")                                                        \
    for (int r_ = 0; r_ < 2; ++r_) dma16(x + tid * 4, scr + wave * 1024);    \
    } while (0)

  f32x4 acc[2][3];
#pragma unroll
  for (int m = 0; m < 2; ++m)
#pragma unroll
    for (int j = 0; j < 3; ++j) acc[m][j] = (f32x4){0.f, 0.f, 0.f, 0.f};

  // prologue: B(0),A(0),B(1),A(1) — 10 DMA/wave; vmcnt(5) forces oldest 5
  QKV_STAGE_B(0, 0); QKV_STAGE_A(0, 0);
  QKV_STAGE_B(1, 1); QKV_STAGE_A(1, 1);

#pragma unroll
  for (int p = 0; p < 16; ++p) {
    asm volatile("s_waitcnt vmcnt(5)" ::: "memory");  // A(p),B(p) landed
    __builtin_amdgcn_s_barrier();                      // raw: no vmcnt(0)
    __builtin_amdgcn_sched_barrier(0);

    if (p + 2 < 16) {
      QKV_STAGE_B(p + 2, (p + 2) % 3);
      QKV_STAGE_A(p + 2, (p + 2) % 3);
    } else {
      QKV_STAGE_B_DUMMY();
      QKV_STAGE_A_DUMMY();
    }
    __builtin_amdgcn_sched_barrier(0);

    const char* ab = Ab[p % 3];
    const char* bb = Bb[p % 3];

    bf16x8 af[2][2];
#pragma unroll
    for (int m = 0; m < 2; ++m) {
      const char* base = ab + (wr * 32 + m * 16 + l15) * 256;
#pragma unroll
      for (int ks = 0; ks < 2; ++ks) {
        int g0 = ks * 8 + lq * 2;
        f32x4 a0 = *(const f32x4*)(base + ((g0 ^ l15) << 4));
        f32x4 a1 = *(const f32x4*)(base + (((g0 + 1) ^ l15) << 4));
        bf16x8 a;
        a[0] = (bf16_t)a0[0]; a[1] = (bf16_t)a0[1]; a[2] = (bf16_t)a0[2]; a[3] = (bf16_t)a0[3];
        a[4] = (bf16_t)a1[0]; a[5] = (bf16_t)a1[1]; a[6] = (bf16_t)a1[2]; a[7] = (bf16_t)a1[3];
        af[m][ks] = a;
      }
    }
    bf16x8 bfv[3][2];
#pragma unroll
    for (int j = 0; j < 3; ++j) {
      const char* cb = bb + (wc * 48 + j * 16 + l15) * 128;
#pragma unroll
      for (int ks = 0; ks < 2; ++ks) {
        int g = ks * 4 + lq;
        bfv[j][ks] = *(const bf16x8*)(cb + ((g ^ (l15 & 7)) << 4));
      }
    }
#pragma unroll
    for (int ks = 0; ks < 2; ++ks)
#pragma unroll
      for (int m = 0; m < 2; ++m)
#pragma unroll
        for (int j = 0; j < 3; ++j)
          acc[m][j] = __builtin_amdgcn_mfma_f32_16x16x32_bf16(af[m][ks], bfv[j][ks], acc[m][j], 0, 0, 0);
  }
  asm volatile("s_waitcnt vmcnt(0)" ::: "memory");  // drain dummies

#undef QKV_STAGE_B
#undef QKV_STAGE_A
#undef QKV_STAGE_B_DUMMY
#undef QKV_STAGE_A_DUMMY

  // epilogue: q row-major * QSCALE; K/V in fragment-tile order
  int wsel_[3], h_[3];
#pragma unroll
  for (int j = 0; j < 3; ++j) {
    int col  = wc * 48 + j * 16 + l15;
    wsel_[j] = col >> 6;
    h_[j]    = col & 63;
  }
#pragma unroll
  for (int m = 0; m < 2; ++m)
#pragma unroll
    for (int j = 0; j < 3; ++j)
#pragma unroll
      for (int r = 0; r < 4; ++r) {
        int mm  = row0 + wr * 32 + m * 16 + lq * 4 + r;
        float v = acc[m][j][r];
        int h   = h_[j];
        if (wsel_[j] == 0) {
          qb[(size_t)mm * H_ + h] = (bf16_t)(v * QSCALE);
        } else {
          int bb2 = mm >> 11, t = mm & 2047;
          int tile = t >> 6;
          size_t base2 = ((size_t)bb2 * 32 + tile) << 12;
          if (wsel_[j] == 1) {
            int n = (t >> 4) & 3, l15k = t & 15;
            int k0 = h >> 5, lqk = (h >> 3) & 3, e = h & 7;
            kb2[base2 + n * 1024 + k0 * 512 + lqk * 128 + l15k * 8 + e] = (bf16_t)v;
          } else {
            int tl = t & 63;
            int k0 = tl >> 5, lqv = (tl >> 3) & 3, ev = tl & 7;
            int nh = h >> 4, l15v = h & 15;
            vt2[base2 + nh * 1024 + k0 * 512 + lqv * 128 + l15v * 8 + ev] = (bf16_t)v;
          }
        }
      }
}

// ---------------------------------------------------------------------------
// Kernel 3a: causal flash attention PARTIALS, split-4, LDS-shared K/V (DMA).
// Grid 1024 = (b<<7)|(qi<<2)|ch. Block = 256 threads = 4 waves (rg = wave).
// (unchanged from R12)
// ---------------------------------------------------------------------------
__global__ __launch_bounds__(256) void attn_partial(
    const bf16_t* __restrict__ qb, const bf16_t* __restrict__ kb2,
    const bf16_t* __restrict__ vt2, bf16_t* __restrict__ opart,
    float* __restrict__ ml) {
  __shared__ bf16_t kvlds[2][8192];   // [buf][ K:0..4095 | V:4096..8191 ]
  __shared__ bf16_t plds[4][16][72];
  const int wave = threadIdx.x >> 6;  // = rg
  const int lane = threadIdx.x & 63;
  const int l15  = lane & 15;
  const int lq   = lane >> 4;
  const int bid  = blockIdx.x;
  const int b    = bid >> 7;
  const int qi   = (bid >> 2) & 31;
  const int ch   = bid & 3;
  const bf16_t* qB = qb + (size_t)b * T_ * H_;
  const int rowbase = qi * 64 + wave * 16;

  bf16x8 qf[2];
#pragma unroll
  for (int k0 = 0; k0 < 2; ++k0)
    qf[k0] = *(const bf16x8*)(qB + (size_t)(rowbase + l15) * H_ + k0 * 32 + lq * 8);

  float m_run = -1e30f;
  float l_part = 0.f;
  f32x4 oacc[4];
#pragma unroll
  for (int nh = 0; nh < 4; ++nh) oacc[nh] = (f32x4){0.f, 0.f, 0.f, 0.f};

  const int nt = (qi >= ch) ? ((qi - ch) >> 2) + 1 : 0;
  const size_t tb = ((size_t)b * 32) << 12;

#define STAGE(KT, BUF)                                                        \
  {                                                                           \
    const bf16_t* kg = kb2 + tb + ((size_t)(KT) << 12) + wave * 1024 + lane * 8; \
    const bf16_t* vg = vt2 + tb + ((size_t)(KT) << 12) + wave * 1024 + lane * 8; \
    bf16_t* kl = &kvlds[BUF][wave * 1024];                                    \
    bf16_t* vl = &kvlds[BUF][4096 + wave * 1024];                             \
    dma16(kg, kl);        dma16(kg + 512, kl + 512);                          \
    dma16(vg, vl);        dma16(vg + 512, vl + 512);                          \
  }

  if (nt > 0) STAGE(ch, 0);
  __syncthreads();

  int kt = ch;
  for (int it = 0; it < nt; ++it, kt += 4) {
    const int buf = it & 1;
    if (it + 1 < nt) STAGE(kt + 4, buf ^ 1);

    const bf16_t* klp = &kvlds[buf][0];
    const bf16_t* vlp = &kvlds[buf][4096];

    bf16x8 kf[4][2];
#pragma unroll
    for (int n = 0; n < 4; ++n)
#pragma unroll
      for (int k0 = 0; k0 < 2; ++k0)
        kf[n][k0] = *(const bf16x8*)(klp + n * 1024 + k0 * 512 + lq * 128 + l15 * 8);

    f32x4 sacc[4];
#pragma unroll
    for (int n = 0; n < 4; ++n) sacc[n] = (f32x4){0.f, 0.f, 0.f, 0.f};
    __builtin_amdgcn_s_setprio(1);
#pragma unroll
    for (int n = 0; n < 4; ++n)
#pragma unroll
      for (int k0 = 0; k0 < 2; ++k0)
        sacc[n] = __builtin_amdgcn_mfma_f32_16x16x32_bf16(kf[n][k0], qf[k0], sacc[n], 0, 0, 0);
    __builtin_amdgcn_s_setprio(0);

    bf16x8 vf[4][2];
#pragma unroll
    for (int nh = 0; nh < 4; ++nh)
#pragma unroll
      for (int k0 = 0; k0 < 2; ++k0)
        vf[nh][k0] = *(const bf16x8*)(vlp + nh * 1024 + k0 * 512 + lq * 128 + l15 * 8);

    if (kt == qi) {
#pragma unroll
      for (int n = 0; n < 4; ++n)
#pragma unroll
        for (int r = 0; r < 4; ++r)
          if (n * 16 + lq * 4 + r > wave * 16 + l15) sacc[n][r] = -1e30f;
    }

    float mx = -1e30f;
#pragma unroll
    for (int n = 0; n < 4; ++n)
#pragma unroll
      for (int r = 0; r < 4; ++r) mx = fmaxf(mx, sacc[n][r]);
    mx = fmaxf(mx, __shfl_xor(mx, 16));
    mx = fmaxf(mx, __shfl_xor(mx, 32));

    if (__any(mx > m_run)) {
      float mnew = fmaxf(m_run, mx);
      float corr = exp2f(m_run - mnew);
      l_part *= corr;
      m_run = mnew;
      float corr4[4];
#pragma unroll
      for (int r = 0; r < 4; ++r) corr4[r] = __shfl(corr, lq * 4 + r);
#pragma unroll
      for (int nh = 0; nh < 4; ++nh)
#pragma unroll
        for (int r = 0; r < 4; ++r) oacc[nh][r] *= corr4[r];
    }

    float psum = 0.f;
#pragma unroll
    for (int n = 0; n < 4; ++n)
#pragma unroll
      for (int r = 0; r < 4; ++r) {
        float p = exp2f(sacc[n][r] - m_run);
        sacc[n][r] = p;
        psum += p;
      }
    l_part += psum;

#pragma unroll
    for (int n = 0; n < 4; ++n) {
      bf16x4 pk;
#pragma unroll
      for (int r = 0; r < 4; ++r) pk[r] = (bf16_t)sacc[n][r];
      *(bf16x4*)&plds[wave][l15][n * 16 + lq * 4] = pk;
    }
    bf16x8 pa[2];
    pa[0] = *(const bf16x8*)&plds[wave][l15][lq * 8];
    pa[1] = *(const bf16x8*)&plds[wave][l15][32 + lq * 8];

    __builtin_amdgcn_s_setprio(1);
#pragma unroll
    for (int nh = 0; nh < 4; ++nh)
#pragma unroll
      for (int k0 = 0; k0 < 2; ++k0)
        oacc[nh] = __builtin_amdgcn_mfma_f32_16x16x32_bf16(pa[k0], vf[nh][k0], oacc[nh], 0, 0, 0);
    __builtin_amdgcn_s_setprio(0);

    __syncthreads();
  }
#undef STAGE

  float l_tot = l_part + __shfl_xor(l_part, 16);
  l_tot += __shfl_xor(l_tot, 32);

  const size_t prow = (size_t)bid * 64 + wave * 16;
#pragma unroll
  for (int r = 0; r < 4; ++r)
#pragma unroll
    for (int nh = 0; nh < 4; ++nh)
      opart[(prow + lq * 4 + r) * 64 + nh * 16 + l15] = (bf16_t)oacc[nh][r];
  if (lq == 0) {
    ml[(prow + l15) * 2 + 0] = m_run;
    ml[(prow + l15) * 2 + 1] = l_tot;
  }
}

// ---------------------------------------------------------------------------
// Kernel 3b: combine 4 kv-chunk partials per (b, qi). Grid 1024.
// ---------------------------------------------------------------------------
__global__ __launch_bounds__(256) void attn_combine(
    const bf16_t* __restrict__ opart, const float* __restrict__ ml,
    float* __restrict__ out) {
  const int bid = blockIdx.x;
  const int cid = bid >> 2;           // (b<<5)|qi
  const int rq  = bid & 3;
  const int b   = cid >> 5;
  const int qi  = cid & 31;
  const int row = rq * 16 + (threadIdx.x >> 4);
  const int c4  = (threadIdx.x & 15) * 4;

  float o0 = 0.f, o1 = 0.f, o2 = 0.f, o3 = 0.f;
  float M = -1e30f, L = 0.f;
#pragma unroll
  for (int s = 0; s < 4; ++s) {
    const size_t prow = (size_t)(cid * 4 + s) * 64 + row;
    float ms = ml[prow * 2 + 0];
    float ls = ml[prow * 2 + 1];
    float Mn = fmaxf(M, ms);
    float a  = exp2f(M - Mn);
    float bs = exp2f(ms - Mn);
    bf16x4 ov = *(const bf16x4*)(opart + prow * 64 + c4);
    o0 = o0 * a + (float)ov[0] * bs;
    o1 = o1 * a + (float)ov[1] * bs;
    o2 = o2 * a + (float)ov[2] * bs;
    o3 = o3 * a + (float)ov[3] * bs;
    L = L * a + ls * bs;
    M = Mn;
  }
  float inv = 1.0f / L;
  float4 v = {o0 * inv, o1 * inv, o2 * inv, o3 * inv};
  *(float4*)(out + ((size_t)b * T_ + qi * 64 + row) * H_ + c4) = v;
}

// ---------------------------------------------------------------------------
extern "C" void kernel_launch(void* const* d_in, const int* in_sizes, int n_in,
                              void* d_out, int out_size, void* d_ws, size_t ws_size,
                              hipStream_t stream) {
  const float* x  = (const float*)d_in[0];
  const float* Wq = (const float*)d_in[1];
  const float* Wk = (const float*)d_in[2];
  const float* Wv = (const float*)d_in[3];

  char* ws = (char*)d_ws;
  bf16_t* Wt    = (bf16_t*)(ws);                     // 384 KB
  bf16_t* qb    = (bf16_t*)(ws + (1u << 20));        // 2 MB (q * QSCALE)
  bf16_t* kb2   = (bf16_t*)(ws + 3u * (1u << 20));   // 2 MB (frag-tile order)
  bf16_t* vt2   = (bf16_t*)(ws + 5u * (1u << 20));   // 2 MB (frag-tile order)
  bf16_t* opart = (bf16_t*)(ws + 8u * (1u << 20));   // 8 MB
  float*  mlbuf = (float*)(ws + 17u * (1u << 20));   // 512 KB
  float*  outp  = (float*)d_out;

  hipLaunchKernelGGL(wprep_kernel, dim3(48), dim3(256), 0, stream, Wq, Wk, Wv, Wt);
  hipLaunchKernelGGL(qkv_kernel, dim3(256), dim3(512), 0, stream, x, Wt, qb, kb2, vt2);
  hipLaunchKernelGGL(attn_partial, dim3(1024), dim3(256), 0, stream, qb, kb2, vt2, opart, mlbuf);
  hipLaunchKernelGGL(attn_combine, dim3(1024), dim3(256), 0, stream, opart, mlbuf, outp);
}